// Round 2
// baseline (24.848 us; speedup 1.0000x reference)
//
#include <hip/hip_runtime.h>

#define FK_EPS 1e-8f
#define BLK 256
#define NJ 24

__global__ __launch_bounds__(BLK, 2)
void fk_kernel(const float* __restrict__ angles,   // (B, 24)
               const float* __restrict__ Torg,     // (24, 4, 4) row-major
               const float* __restrict__ axes,     // (24, 3)
               float* __restrict__ out,            // (B, 75)
               int B)
{
    __shared__ float sT[NJ * 16];    // 384 floats
    __shared__ float sAx[NJ * 3];    // 72 floats
    __shared__ float stage[BLK * 75];

    const int tid = threadIdx.x;
    // NJ*16 = 384 > BLK: must stride, a single predicated store misses 256..383
    for (int i = tid; i < NJ * 16; i += BLK) sT[i] = Torg[i];
    if (tid < NJ * 3) sAx[tid] = axes[tid];
    __syncthreads();

    const int b = blockIdx.x * BLK + tid;

    // Preload this thread's 24 joint angles as 6x float4 (contiguous 96 B).
    float a[NJ];
    {
        const float4* ap = reinterpret_cast<const float4*>(angles + (size_t)b * NJ);
        #pragma unroll
        for (int q = 0; q < 6; ++q) {
            float4 v = ap[q];
            a[q*4+0] = v.x; a[q*4+1] = v.y; a[q*4+2] = v.z; a[q*4+3] = v.w;
        }
    }

    // Running affine transform T = [R | t] (row 3 implicit [0,0,0,1]).
    float t00 = 1.f, t01 = 0.f, t02 = 0.f;
    float t10 = 0.f, t11 = 1.f, t12 = 0.f;
    float t20 = 0.f, t21 = 0.f, t22 = 1.f;
    float tx = 0.f, ty = 0.f, tz = 0.f;

    float* srow = &stage[tid * 75];
    srow[0] = 0.f; srow[1] = 0.f; srow[2] = 0.f;   // base_pos

    #pragma unroll
    for (int j = 0; j < NJ; ++j) {
        const float* o = &sT[j * 16];
        const float o00 = o[0], o01 = o[1], o02 = o[2],  ox = o[3];
        const float o10 = o[4], o11 = o[5], o12 = o[6],  oy = o[7];
        const float o20 = o[8], o21 = o[9], o22 = o[10], oz = o[11];

        // M = T * T_org   (rotation part), p = its translation
        const float m00 = t00*o00 + t01*o10 + t02*o20;
        const float m01 = t00*o01 + t01*o11 + t02*o21;
        const float m02 = t00*o02 + t01*o12 + t02*o22;
        const float m10 = t10*o00 + t11*o10 + t12*o20;
        const float m11 = t10*o01 + t11*o11 + t12*o21;
        const float m12 = t10*o02 + t11*o12 + t12*o22;
        const float m20 = t20*o00 + t21*o10 + t22*o20;
        const float m21 = t20*o01 + t21*o11 + t22*o21;
        const float m22 = t20*o02 + t21*o12 + t22*o22;

        const float px = t00*ox + t01*oy + t02*oz + tx;
        const float py = t10*ox + t11*oy + t12*oz + ty;
        const float pz = t20*ox + t21*oy + t22*oz + tz;

        // Rodrigues rotation for joint j: aa = axis * angle
        const float ang = a[j];
        const float kx = sAx[j*3+0] * ang;
        const float ky = sAx[j*3+1] * ang;
        const float kz = sAx[j*3+2] * ang;
        const float th2 = kx*kx + ky*ky + kz*kz;
        const float theta = sqrtf(th2);
        float s, c;
        __sincosf(theta, &s, &c);

        const float t2e = theta * theta + FK_EPS;
        float A  = s / (theta + FK_EPS);
        float Bc = (1.f - c) / t2e;
        // small-angle Taylor branch (matches reference's jnp.where)
        {
            const float h2 = theta * theta, h4 = h2 * h2;
            const float At = 1.f - h2 * (1.f/6.f)  + h4 * (1.f/120.f);
            const float Bt = 0.5f - h2 * (1.f/24.f) + h4 * (1.f/720.f);
            const bool small = theta < 1e-3f;
            A  = small ? At : A;
            Bc = small ? Bt : Bc;
        }

        // R = I + A*K + Bc*(k k^T - th2*I), K = skew(k)
        const float r00 = 1.f + Bc * (kx*kx - th2);
        const float r01 = Bc * kx*ky - A * kz;
        const float r02 = Bc * kx*kz + A * ky;
        const float r10 = Bc * kx*ky + A * kz;
        const float r11 = 1.f + Bc * (ky*ky - th2);
        const float r12 = Bc * ky*kz - A * kx;
        const float r20 = Bc * kx*kz - A * ky;
        const float r21 = Bc * ky*kz + A * kx;
        const float r22 = 1.f + Bc * (kz*kz - th2);

        // T = M * R (rotation), translation = p
        t00 = m00*r00 + m01*r10 + m02*r20;
        t01 = m00*r01 + m01*r11 + m02*r21;
        t02 = m00*r02 + m01*r12 + m02*r22;
        t10 = m10*r00 + m11*r10 + m12*r20;
        t11 = m10*r01 + m11*r11 + m12*r21;
        t12 = m10*r02 + m11*r12 + m12*r22;
        t20 = m20*r00 + m21*r10 + m22*r20;
        t21 = m20*r01 + m21*r11 + m22*r21;
        t22 = m20*r02 + m21*r12 + m22*r22;
        tx = px; ty = py; tz = pz;

        srow[3 + 3*j + 0] = px;
        srow[3 + 3*j + 1] = py;
        srow[3 + 3*j + 2] = pz;
    }

    __syncthreads();

    // Coalesced float4 writeout of the whole block's 256x75 stage.
    float4* out4 = reinterpret_cast<float4*>(out + (size_t)blockIdx.x * BLK * 75);
    const float4* st4 = reinterpret_cast<const float4*>(stage);
    #pragma unroll 1
    for (int i = tid; i < BLK * 75 / 4; i += BLK) {
        out4[i] = st4[i];
    }
}

extern "C" void kernel_launch(void* const* d_in, const int* in_sizes, int n_in,
                              void* d_out, int out_size, void* d_ws, size_t ws_size,
                              hipStream_t stream) {
    const float* angles = (const float*)d_in[0];
    const float* Torg   = (const float*)d_in[1];
    const float* axes   = (const float*)d_in[2];
    float* out = (float*)d_out;

    const int B = in_sizes[0] / NJ;          // 131072
    const int grid = (B + BLK - 1) / BLK;    // 512

    fk_kernel<<<grid, BLK, 0, stream>>>(angles, Torg, axes, out, B);
}

// Round 3
// 23.979 us; speedup vs baseline: 1.0363x; 1.0363x over previous
//
#include <hip/hip_runtime.h>

#define FK_EPS 1e-8f
#define BLK 256
#define NJ 24

__global__ __launch_bounds__(BLK, 2)
void fk_kernel(const float* __restrict__ angles,   // (B, 24)
               const float* __restrict__ Torg,     // (24, 4, 4) row-major
               const float* __restrict__ axes,     // (24, 3)
               float* __restrict__ out,            // (B, 75)
               int B)
{
    // Output staging only. Constants now come via scalar loads (uniform
    // compile-time indices -> s_load + SGPR broadcast), not LDS.
    __shared__ float stage[BLK * 75];

    const int tid = threadIdx.x;
    const int b = blockIdx.x * BLK + tid;

    // Preload this thread's 24 joint angles as 6x float4 (contiguous 96 B).
    float a[NJ];
    {
        const float4* ap = reinterpret_cast<const float4*>(angles + (size_t)b * NJ);
        #pragma unroll
        for (int q = 0; q < 6; ++q) {
            float4 v = ap[q];
            a[q*4+0] = v.x; a[q*4+1] = v.y; a[q*4+2] = v.z; a[q*4+3] = v.w;
        }
    }

    // Running affine transform T = [R | t] (row 3 implicit [0,0,0,1]).
    float t00 = 1.f, t01 = 0.f, t02 = 0.f;
    float t10 = 0.f, t11 = 1.f, t12 = 0.f;
    float t20 = 0.f, t21 = 0.f, t22 = 1.f;
    float tx = 0.f, ty = 0.f, tz = 0.f;

    float* srow = &stage[tid * 75];
    srow[0] = 0.f; srow[1] = 0.f; srow[2] = 0.f;   // base_pos

    #pragma unroll
    for (int j = 0; j < NJ; ++j) {
        // Uniform constant reads: j is a compile-time constant after unroll,
        // pointers are __restrict__ const -> backend emits s_load (SGPR).
        const float o00 = Torg[j*16+0],  o01 = Torg[j*16+1],  o02 = Torg[j*16+2],  ox = Torg[j*16+3];
        const float o10 = Torg[j*16+4],  o11 = Torg[j*16+5],  o12 = Torg[j*16+6],  oy = Torg[j*16+7];
        const float o20 = Torg[j*16+8],  o21 = Torg[j*16+9],  o22 = Torg[j*16+10], oz = Torg[j*16+11];
        const float axx = axes[j*3+0], axy = axes[j*3+1], axz = axes[j*3+2];

        // M = T * T_org   (rotation part), p = its translation
        const float m00 = t00*o00 + t01*o10 + t02*o20;
        const float m01 = t00*o01 + t01*o11 + t02*o21;
        const float m02 = t00*o02 + t01*o12 + t02*o22;
        const float m10 = t10*o00 + t11*o10 + t12*o20;
        const float m11 = t10*o01 + t11*o11 + t12*o21;
        const float m12 = t10*o02 + t11*o12 + t12*o22;
        const float m20 = t20*o00 + t21*o10 + t22*o20;
        const float m21 = t20*o01 + t21*o11 + t22*o21;
        const float m22 = t20*o02 + t21*o12 + t22*o22;

        const float px = t00*ox + t01*oy + t02*oz + tx;
        const float py = t10*ox + t11*oy + t12*oz + ty;
        const float pz = t20*ox + t21*oy + t22*oz + tz;

        // Rodrigues rotation for joint j: aa = axis * angle
        const float ang = a[j];
        const float kx = axx * ang;
        const float ky = axy * ang;
        const float kz = axz * ang;
        const float th2 = kx*kx + ky*ky + kz*kz;
        const float theta = sqrtf(th2);
        float s, c;
        __sincosf(theta, &s, &c);

        const float t2e = theta * theta + FK_EPS;
        float A  = s / (theta + FK_EPS);
        float Bc = (1.f - c) / t2e;
        // small-angle Taylor branch (matches reference's jnp.where)
        {
            const float h2 = theta * theta, h4 = h2 * h2;
            const float At = 1.f - h2 * (1.f/6.f)  + h4 * (1.f/120.f);
            const float Bt = 0.5f - h2 * (1.f/24.f) + h4 * (1.f/720.f);
            const bool small = theta < 1e-3f;
            A  = small ? At : A;
            Bc = small ? Bt : Bc;
        }

        // R = I + A*K + Bc*(k k^T - th2*I), K = skew(k)
        const float r00 = 1.f + Bc * (kx*kx - th2);
        const float r01 = Bc * kx*ky - A * kz;
        const float r02 = Bc * kx*kz + A * ky;
        const float r10 = Bc * kx*ky + A * kz;
        const float r11 = 1.f + Bc * (ky*ky - th2);
        const float r12 = Bc * ky*kz - A * kx;
        const float r20 = Bc * kx*kz - A * ky;
        const float r21 = Bc * ky*kz + A * kx;
        const float r22 = 1.f + Bc * (kz*kz - th2);

        // T = M * R (rotation), translation = p
        t00 = m00*r00 + m01*r10 + m02*r20;
        t01 = m00*r01 + m01*r11 + m02*r21;
        t02 = m00*r02 + m01*r12 + m02*r22;
        t10 = m10*r00 + m11*r10 + m12*r20;
        t11 = m10*r01 + m11*r11 + m12*r21;
        t12 = m10*r02 + m11*r12 + m12*r22;
        t20 = m20*r00 + m21*r10 + m22*r20;
        t21 = m20*r01 + m21*r11 + m22*r21;
        t22 = m20*r02 + m21*r12 + m22*r22;
        tx = px; ty = py; tz = pz;

        srow[3 + 3*j + 0] = px;
        srow[3 + 3*j + 1] = py;
        srow[3 + 3*j + 2] = pz;
    }

    __syncthreads();

    // Coalesced float4 writeout of the whole block's 256x75 stage.
    float4* out4 = reinterpret_cast<float4*>(out + (size_t)blockIdx.x * BLK * 75);
    const float4* st4 = reinterpret_cast<const float4*>(stage);
    #pragma unroll 1
    for (int i = tid; i < BLK * 75 / 4; i += BLK) {
        out4[i] = st4[i];
    }
}

extern "C" void kernel_launch(void* const* d_in, const int* in_sizes, int n_in,
                              void* d_out, int out_size, void* d_ws, size_t ws_size,
                              hipStream_t stream) {
    const float* angles = (const float*)d_in[0];
    const float* Torg   = (const float*)d_in[1];
    const float* axes   = (const float*)d_in[2];
    float* out = (float*)d_out;

    const int B = in_sizes[0] / NJ;          // 131072
    const int grid = (B + BLK - 1) / BLK;    // 512

    fk_kernel<<<grid, BLK, 0, stream>>>(angles, Torg, axes, out, B);
}

// Round 4
// 22.519 us; speedup vs baseline: 1.1034x; 1.0648x over previous
//
#include <hip/hip_runtime.h>

#define FK_EPS 1e-8f
#define BLK 256
#define NJ 24
#define G 8

__global__ __launch_bounds__(BLK, 2)
void fk_kernel(const float* __restrict__ angles,   // (B, 24)
               const float* __restrict__ Torg,     // (24, 4, 4) row-major
               const float* __restrict__ axes,     // (24, 3)
               float* __restrict__ out,            // (B, 75)
               int B)
{
    __shared__ float stage[BLK * 75];

    const int tid = threadIdx.x;
    const int b = blockIdx.x * BLK + tid;

    // Running affine transform T = [R | t] (row 3 implicit [0,0,0,1]).
    float t00 = 1.f, t01 = 0.f, t02 = 0.f;
    float t10 = 0.f, t11 = 1.f, t12 = 0.f;
    float t20 = 0.f, t21 = 0.f, t22 = 1.f;
    float tx = 0.f, ty = 0.f, tz = 0.f;

    float* srow = &stage[tid * 75];
    srow[0] = 0.f; srow[1] = 0.f; srow[2] = 0.f;   // base_pos

    // Rolled group loop (3 iters) keeps code ~1/3 size (L1I), while the
    // inner unrolls give 8-wide ILP on the transcendental chains.
    #pragma unroll 1
    for (int g = 0; g < NJ / G; ++g) {
        // --- Phase A: 8 independent Rodrigues builds (chain-free ILP) ---
        // Angles for this group: 8 consecutive floats, 32B-aligned.
        float a[G];
        {
            const float4* ap =
                reinterpret_cast<const float4*>(angles + (size_t)b * NJ + g * G);
            float4 v0 = ap[0], v1 = ap[1];
            a[0]=v0.x; a[1]=v0.y; a[2]=v0.z; a[3]=v0.w;
            a[4]=v1.x; a[5]=v1.y; a[6]=v1.z; a[7]=v1.w;
        }

        float R[G][9];
        #pragma unroll
        for (int u = 0; u < G; ++u) {
            const int j = g * G + u;           // uniform: axes reads stay scalar
            const float ang = a[u];
            const float kx = axes[j*3+0] * ang;
            const float ky = axes[j*3+1] * ang;
            const float kz = axes[j*3+2] * ang;
            const float th2 = kx*kx + ky*ky + kz*kz;
            const float theta = __builtin_amdgcn_sqrtf(th2);
            const float s = __sinf(theta);
            const float c = __cosf(theta);

            float A  = s * __builtin_amdgcn_rcpf(theta + FK_EPS);
            float Bc = (1.f - c) * __builtin_amdgcn_rcpf(theta * theta + FK_EPS);
            {   // small-angle Taylor select (matches reference's jnp.where)
                const float h2 = theta * theta, h4 = h2 * h2;
                const float At = 1.f  - h2 * (1.f/6.f)  + h4 * (1.f/120.f);
                const float Bt = 0.5f - h2 * (1.f/24.f) + h4 * (1.f/720.f);
                const bool small = theta < 1e-3f;
                A  = small ? At : A;
                Bc = small ? Bt : Bc;
            }

            // R = I + A*K + Bc*(k k^T - th2*I), K = skew(k)
            R[u][0] = 1.f + Bc * (kx*kx - th2);
            R[u][1] = Bc * kx*ky - A * kz;
            R[u][2] = Bc * kx*kz + A * ky;
            R[u][3] = Bc * kx*ky + A * kz;
            R[u][4] = 1.f + Bc * (ky*ky - th2);
            R[u][5] = Bc * ky*kz - A * kx;
            R[u][6] = Bc * kx*kz - A * ky;
            R[u][7] = Bc * ky*kz + A * kx;
            R[u][8] = 1.f + Bc * (kz*kz - th2);
        }

        // --- Phase B: pure-FMA serial chain through the 8 joints ---
        #pragma unroll
        for (int u = 0; u < G; ++u) {
            const int j = g * G + u;
            const float o00 = Torg[j*16+0],  o01 = Torg[j*16+1],  o02 = Torg[j*16+2],  ox = Torg[j*16+3];
            const float o10 = Torg[j*16+4],  o11 = Torg[j*16+5],  o12 = Torg[j*16+6],  oy = Torg[j*16+7];
            const float o20 = Torg[j*16+8],  o21 = Torg[j*16+9],  o22 = Torg[j*16+10], oz = Torg[j*16+11];

            // M = T * T_org (rotation), p = its translation
            const float m00 = t00*o00 + t01*o10 + t02*o20;
            const float m01 = t00*o01 + t01*o11 + t02*o21;
            const float m02 = t00*o02 + t01*o12 + t02*o22;
            const float m10 = t10*o00 + t11*o10 + t12*o20;
            const float m11 = t10*o01 + t11*o11 + t12*o21;
            const float m12 = t10*o02 + t11*o12 + t12*o22;
            const float m20 = t20*o00 + t21*o10 + t22*o20;
            const float m21 = t20*o01 + t21*o11 + t22*o21;
            const float m22 = t20*o02 + t21*o12 + t22*o22;

            const float px = t00*ox + t01*oy + t02*oz + tx;
            const float py = t10*ox + t11*oy + t12*oz + ty;
            const float pz = t20*ox + t21*oy + t22*oz + tz;

            // T = M * R[u]
            const float r00 = R[u][0], r01 = R[u][1], r02 = R[u][2];
            const float r10 = R[u][3], r11 = R[u][4], r12 = R[u][5];
            const float r20 = R[u][6], r21 = R[u][7], r22 = R[u][8];

            t00 = m00*r00 + m01*r10 + m02*r20;
            t01 = m00*r01 + m01*r11 + m02*r21;
            t02 = m00*r02 + m01*r12 + m02*r22;
            t10 = m10*r00 + m11*r10 + m12*r20;
            t11 = m10*r01 + m11*r11 + m12*r21;
            t12 = m10*r02 + m11*r12 + m12*r22;
            t20 = m20*r00 + m21*r10 + m22*r20;
            t21 = m20*r01 + m21*r11 + m22*r21;
            t22 = m20*r02 + m21*r12 + m22*r22;
            tx = px; ty = py; tz = pz;

            srow[3 + 3*j + 0] = px;
            srow[3 + 3*j + 1] = py;
            srow[3 + 3*j + 2] = pz;
        }
    }

    __syncthreads();

    // Coalesced float4 writeout of the whole block's 256x75 stage.
    float4* out4 = reinterpret_cast<float4*>(out + (size_t)blockIdx.x * BLK * 75);
    const float4* st4 = reinterpret_cast<const float4*>(stage);
    #pragma unroll 1
    for (int i = tid; i < BLK * 75 / 4; i += BLK) {
        out4[i] = st4[i];
    }
}

extern "C" void kernel_launch(void* const* d_in, const int* in_sizes, int n_in,
                              void* d_out, int out_size, void* d_ws, size_t ws_size,
                              hipStream_t stream) {
    const float* angles = (const float*)d_in[0];
    const float* Torg   = (const float*)d_in[1];
    const float* axes   = (const float*)d_in[2];
    float* out = (float*)d_out;

    const int B = in_sizes[0] / NJ;          // 131072
    const int grid = (B + BLK - 1) / BLK;    // 512

    fk_kernel<<<grid, BLK, 0, stream>>>(angles, Torg, axes, out, B);
}